// Round 11
// baseline (22697.514 us; speedup 1.0000x reference)
//
#include <hip/hip_runtime.h>
#include <math.h>

#define BB 32
#define SS 64
#define HH 256
#define G4 1024
#define NT 1024

// ws float offsets (R9 layout)
#define W1T_OFF 2097152
#define W2T_OFF 2162688
#define PB_OFF  2228224
#define PBB     115712
#define OX1     0
#define OH1     65536
#define OP2     81920
#define OH2     98304
#define ODC1    114688
#define ODC2    114944
#define FLG_OFF (PB_OFF + 32*PBB)
#define NFLGW   (32*256 + 32)
#define X1B_OFF (FLG_OFF + NFLGW)
#define FA 0
#define FB 32
#define FC 64
#define FD 96

__device__ __forceinline__ float sigmf(float x){ return 1.f/(1.f+expf(-x)); }
__device__ __forceinline__ float dot4(float4 a, float4 b){
  return fmaf(a.x,b.x,fmaf(a.y,b.y,fmaf(a.z,b.z,a.w*b.w)));
}
// Relaxed agent-scope transport (R7/R9-proven). Ordering: payload srel ->
// drain_vm -> barrier -> flag fst. One-directional waits only.
__device__ __forceinline__ void fst(unsigned* p, unsigned v){
  __hip_atomic_store(p, v, __ATOMIC_RELAXED, __HIP_MEMORY_SCOPE_AGENT);
}
__device__ __forceinline__ unsigned fld(unsigned* p){
  return __hip_atomic_load(p, __ATOMIC_RELAXED, __HIP_MEMORY_SCOPE_AGENT);
}
__device__ __forceinline__ void srel(float* p, float v){
  __hip_atomic_store(p, v, __ATOMIC_RELAXED, __HIP_MEMORY_SCOPE_AGENT);
}
__device__ __forceinline__ float lrel(const float* p){
  return __hip_atomic_load((float*)p, __ATOMIC_RELAXED, __HIP_MEMORY_SCOPE_AGENT);
}
__device__ __forceinline__ void drain_vm(){
  asm volatile("s_waitcnt vmcnt(0)" ::: "memory");
}
__device__ __forceinline__ int wait_ge(unsigned* p, unsigned want, unsigned* ab){
  int it = 0;
  for(;;){
    unsigned v = fld(p);
    if (v >= want) return (int)v;
    if ((++it & 2047) == 0){
      if (fld(ab) != 0u) return -1;
      if (it > (1<<23)){ fst(ab, 1u); return -1; }
    }
    __builtin_amdgcn_s_sleep(2);
  }
}

__global__ void zflags_k(float* ws){
  unsigned* f = (unsigned*)(ws + FLG_OFF);
  int i = blockIdx.x*1024 + threadIdx.x;
  if (i < NFLGW) f[i] = 0u;
}

// R2-validated pack: dst[((k>>2)*1024 + g)*4 + (k&3)] = src[g*256 + k]
__global__ void pack_transpose_k(const float* __restrict__ s0, const float* __restrict__ s1,
                                 const float* __restrict__ s2, const float* __restrict__ s3,
                                 const float* __restrict__ s4, const float* __restrict__ s5,
                                 const float* __restrict__ s6, const float* __restrict__ s7,
                                 float* __restrict__ ws) {
    __shared__ float tile[64][65];
    const float* srcs[8] = {s0, s1, s2, s3, s4, s5, s6, s7};
    const float* src = srcs[blockIdx.z];
    float* dst = ws + (size_t)blockIdx.z * (G4 * HH);
    int gblk = blockIdx.x * 64;
    int kblk = blockIdx.y * 64;
    for (int q = threadIdx.x; q < 64 * 64; q += 256) {
        int r = q >> 6, c = q & 63;
        tile[r][c] = src[(size_t)(gblk + r) * HH + (kblk + c)];
    }
    __syncthreads();
    for (int q = threadIdx.x; q < 64 * 64; q += 256) {
        int r = q & 3;
        int gl = (q >> 2) & 63;
        int k0l = q >> 8;
        int dsti = (((kblk >> 2) + k0l) * G4 + gblk + gl) * 4 + r;
        dst[dsti] = tile[gl][k0l * 4 + r];
    }
}

// dst[k*256+j] = src[j*256+k]
__global__ void transpose256_k(const float* __restrict__ W1, const float* __restrict__ W2,
                               float* __restrict__ ws) {
    __shared__ float tile[32][33];
    const float* src = blockIdx.z ? W2 : W1;
    float* dst = ws + (blockIdx.z ? W2T_OFF : W1T_OFF);
    int j0 = blockIdx.x * 32, k0 = blockIdx.y * 32;
    int tx = threadIdx.x & 31, ty = threadIdx.x >> 5;
    for (int i = ty; i < 32; i += 8) tile[i][tx] = src[(size_t)(j0 + i) * HH + k0 + tx];
    __syncthreads();
    for (int i = ty; i < 32; i += 8) dst[(size_t)(k0 + i) * HH + j0 + tx] = tile[tx][i];
}

__global__ void __launch_bounds__(NT) ptrnet_k(
    const float* __restrict__ inputs, const float* __restrict__ W_emb,
    const float* __restrict__ b_emb,
    const float* __restrict__ b_e0, const float* __restrict__ b_e1,
    const float* __restrict__ b_d0, const float* __restrict__ b_d1,
    const float* __restrict__ vv,
    float* __restrict__ ws, float* __restrict__ out, int useX1B) {
  const int g = blockIdx.x;
  // R9 mapping (measured best): role = g&3, XCD = g%8 -> XCDs {0,4}=A {1,5}=B
  // {2,6}=C {3,7}=D, so each XCD's L2 hot set is ONE role's ~2MB weight pack.
  const int role = g & 3;
  const int b    = g >> 2;
  const int tid = threadIdx.x;

  const float4* ws4 = (const float4*)ws;
  const float4* We0ih = ws4 + 0*65536;
  const float4* We0hh = ws4 + 1*65536;
  const float4* We1ih = ws4 + 2*65536;
  const float4* We1hh = ws4 + 3*65536;
  const float4* Wd0ih = ws4 + 4*65536;
  const float4* Wd0hh = ws4 + 5*65536;
  const float4* Wd1ih = ws4 + 6*65536;
  const float4* Wd1hh = ws4 + 7*65536;
  const float* W1T = ws + W1T_OFF;
  const float* W2T = ws + W2T_OFF;

  float* pb   = ws + PB_OFF + (size_t)b * PBB;
  float* X1   = pb + OX1;    // A-private
  float* h1cw = pb + OH1;    // A -> B
  float* p2cw = pb + OP2;    // B -> C, ring 16
  float* h2cw = pb + OH2;    // C -> D
  float* dc1i = pb + ODC1;   // A -> D (pass-0 finals)
  float* dc2i = pb + ODC2;   // C -> D
  float* X1B  = ws + X1B_OFF + (size_t)b * 65536;  // A-private (guarded)
  unsigned* Wf  = (unsigned*)(ws + FLG_OFF);
  unsigned* flg = Wf + b*256;   // each flag on its own 128B line
  unsigned* abw = Wf + 32*256;

  __shared__ float big0[16384];  // A: preE->c1c; C: c2c; D: preE
  __shared__ float big1[16384];  // A: init staging -> h1 history; C: h2 history; D: eW1
  __shared__ float gbuf[1024];
  __shared__ float v0[256], v1[256], v2[256], v3[256], v4[256], v5[256], v6[256];
  __shared__ float scr[64];
  __shared__ float smax_s;
  __shared__ int msk[64];
  __shared__ int ibc[2];

  // ================= role A: layer-1 recurrence =================
  if (role == 0) {
    for (int i = tid; i < SS*HH; i += NT){
      int t = i >> 8, j = i & 255;
      const float* xr = inputs + ((size_t)b*SS + t)*8;
      float acc = b_emb[j];
#pragma unroll
      for (int d = 0; d < 8; ++d) acc = fmaf(xr[d], W_emb[j*8+d], acc);
      big0[i] = acc;  // preE
    }
    __syncthreads();
    // X1 (+X1alt) init: 16 tiles of 4 t, one weight stream serves both
    for (int tile = 0; tile < 16; ++tile){
      { int tt = tid >> 8, j = tid & 255;
        float pe = big0[(tile*4+tt)*256 + j];
        gbuf[tid] = tanhf(pe);
        big1[tid] = tanhf(pe + W_emb[j*8 + 7]); }
      __syncthreads();
      float a0=0.f,a1=0.f,a2=0.f,a3=0.f;
      float c0=0.f,c1=0.f,c2=0.f,c3=0.f;
      for (int kq = 0; kq < 64; ++kq){
        float4 w = We0ih[(kq<<10) + tid];
        a0 += dot4(w, *(const float4*)&gbuf[   0 + kq*4]);
        a1 += dot4(w, *(const float4*)&gbuf[ 256 + kq*4]);
        a2 += dot4(w, *(const float4*)&gbuf[ 512 + kq*4]);
        a3 += dot4(w, *(const float4*)&gbuf[ 768 + kq*4]);
        c0 += dot4(w, *(const float4*)&big1[   0 + kq*4]);
        c1 += dot4(w, *(const float4*)&big1[ 256 + kq*4]);
        c2 += dot4(w, *(const float4*)&big1[ 512 + kq*4]);
        c3 += dot4(w, *(const float4*)&big1[ 768 + kq*4]);
      }
      float bg = b_e0[tid];
      X1[(tile*4+0)*1024 + tid] = bg + a0;
      X1[(tile*4+1)*1024 + tid] = bg + a1;
      X1[(tile*4+2)*1024 + tid] = bg + a2;
      X1[(tile*4+3)*1024 + tid] = bg + a3;
      if (useX1B){
        X1B[(tile*4+0)*1024 + tid] = bg + c0;
        X1B[(tile*4+1)*1024 + tid] = bg + c1;
        X1B[(tile*4+2)*1024 + tid] = bg + c2;
        X1B[(tile*4+3)*1024 + tid] = bg + c3;
      }
      __syncthreads();
    }
    // big0 -> c1c; big1 -> h1 history (LDS-local restart state)
    if (tid < 256) v0[tid] = 0.f;  // h1
    __syncthreads();
    int tau = 0;
    for (int p = 0; p < SS; ++p){
      int t0 = 0;
      float xr0 = 0.f;
      if (p > 0){
        if (tid == 0){
          int iv = wait_ge(&flg[FD], (unsigned)p << 8, abw);
          ibc[0] = (iv < 0) ? 0 : (iv & 255);
        }
        __syncthreads();
        t0 = ibc[0];
        if (useX1B){
          xr0 = X1B[t0*1024 + tid];     // precomputed flagged row
        } else {
          if (tid < 256){               // fallback: recompute embt + GEMV
            const float* xr = inputs + ((size_t)b*SS + t0)*8;
            float pe = b_emb[tid];
#pragma unroll
            for (int d = 0; d < 8; ++d) pe = fmaf(xr[d], W_emb[tid*8+d], pe);
            v1[tid] = tanhf(pe + W_emb[tid*8 + 7]);
          }
          __syncthreads();
          float accR = 0.f;
          for (int kq = 0; kq < 64; ++kq)
            accR += dot4(We0ih[(kq<<10) + tid], *(const float4*)&v1[kq*4]);
          xr0 = b_e0[tid] + accR;
        }
        X1[t0*1024 + tid] = xr0;        // permanent (cur flags accumulate)
        if (tid < 256) v0[tid] = (t0 > 0) ? big1[(t0-1)*256 + tid] : 0.f;  // LDS history
        __syncthreads();
      }
      for (int t = t0; t < SS; ++t){
        ++tau;
        float xv = (p > 0 && t == t0) ? xr0 : X1[t*1024 + tid];
        float acc = 0.f;
        for (int kq = 0; kq < 64; ++kq)
          acc += dot4(We0hh[(kq<<10) + tid], *(const float4*)&v0[kq*4]);
        gbuf[tid] = acc + xv;
        __syncthreads();
        if (tid < 256){
          float Gi = gbuf[tid], Gf = gbuf[tid+256], Gg = gbuf[tid+512], Go = gbuf[tid+768];
          float cp = (t == 0) ? 0.f : big0[(t-1)*256 + tid];
          float cc = sigmf(Gf)*cp + sigmf(Gi)*tanhf(Gg);
          float hh = sigmf(Go)*tanhf(cc);
          big0[t*256 + tid] = cc; v0[tid] = hh;
          big1[t*256 + tid] = hh;                 // local history
          srel(&h1cw[t*256 + tid], hh);
          if (p == 0 && t == SS-1) srel(&dc1i[tid], cc);
        }
        drain_vm();
        __syncthreads();
        if (tid == 0) fst(&flg[FA], (unsigned)tau);
      }
    }
  }
  // ================= role B: p2(t) = b_e1 + Wih1 . h1(t) =================
  else if (role == 1) {
    int tau = 0;
    for (int p = 0; p < SS; ++p){
      int t0 = 0;
      if (p > 0){
        if (tid == 0){
          int iv = wait_ge(&flg[FD], (unsigned)p << 8, abw);
          ibc[0] = (iv < 0) ? 0 : (iv & 255);
        }
        __syncthreads();
        t0 = ibc[0];
      }
      for (int t = t0; t < SS; ++t){
        ++tau;
        if (tid == 0){
          wait_ge(&flg[FA], (unsigned)tau, abw);
          if (tau > 16) wait_ge(&flg[FC], (unsigned)(tau-16), abw);
        }
        __syncthreads();
        if (tid < 256) v0[tid] = lrel(&h1cw[t*256 + tid]);
        __syncthreads();
        float acc = b_e1[tid];
        for (int kq = 0; kq < 64; ++kq)
          acc += dot4(We1ih[(kq<<10) + tid], *(const float4*)&v0[kq*4]);
        srel(&p2cw[(tau & 15)*1024 + tid], acc);
        drain_vm();
        __syncthreads();
        if (tid == 0) fst(&flg[FB], (unsigned)tau);
      }
    }
  }
  // ================= role C: layer-2 recurrence =================
  else if (role == 2) {
    int tau = 0;
    for (int p = 0; p < SS; ++p){
      int t0 = 0;
      if (p > 0){
        if (tid == 0){
          int iv = wait_ge(&flg[FD], (unsigned)p << 8, abw);
          ibc[0] = (iv < 0) ? 0 : (iv & 255);
        }
        __syncthreads();
        t0 = ibc[0];
      }
      if (tid < 256) v0[tid] = (t0 > 0) ? big1[(t0-1)*256 + tid] : 0.f;  // LDS history
      __syncthreads();
      for (int t = t0; t < SS; ++t){
        ++tau;
        if (tid == 0) wait_ge(&flg[FB], (unsigned)tau, abw);
        __syncthreads();
        float p2v = lrel(&p2cw[(tau & 15)*1024 + tid]);  // in flight during GEMV
        float acc = 0.f;
        for (int kq = 0; kq < 64; ++kq)
          acc += dot4(We1hh[(kq<<10) + tid], *(const float4*)&v0[kq*4]);
        gbuf[tid] = acc + p2v;
        __syncthreads();
        if (tid < 256){
          float Gi = gbuf[tid], Gf = gbuf[tid+256], Gg = gbuf[tid+512], Go = gbuf[tid+768];
          float cp = (t == 0) ? 0.f : big0[(t-1)*256 + tid];   // c2c
          float cc = sigmf(Gf)*cp + sigmf(Gi)*tanhf(Gg);
          float hh = sigmf(Go)*tanhf(cc);
          big0[t*256 + tid] = cc; v0[tid] = hh;
          big1[t*256 + tid] = hh;                 // local history
          srel(&h2cw[t*256 + tid], hh);
          if (p == 0 && t == SS-1) srel(&dc2i[tid], cc);
        }
        drain_vm();
        __syncthreads();
        if (tid == 0) fst(&flg[FC], (unsigned)tau);
      }
    }
  }
  // ================= role D: eW1, decoder cell, attention, argmax =================
  else {
    for (int i = tid; i < SS*HH; i += NT){
      int t = i >> 8, j = i & 255;
      const float* xr = inputs + ((size_t)b*SS + t)*8;
      float acc = b_emb[j];
#pragma unroll
      for (int d = 0; d < 8; ++d) acc = fmaf(xr[d], W_emb[j*8+d], acc);
      big0[i] = acc;  // preE, kept whole run
    }
    if (tid < 64) msk[tid] = 0;
    __syncthreads();

    // v2=dins v3=dh1 v4=dc1 v5=dh2 v6=dc2 v1=a2
    auto dec_cell = [&](){
      { float acc = b_d0[tid];
        for (int kq = 0; kq < 64; ++kq){
          acc += dot4(Wd0ih[(kq<<10) + tid], *(const float4*)&v2[kq*4]);
          acc += dot4(Wd0hh[(kq<<10) + tid], *(const float4*)&v3[kq*4]);
        }
        gbuf[tid] = acc; }
      __syncthreads();
      if (tid < 256){
        float Gi = gbuf[tid], Gf = gbuf[tid+256], Gg = gbuf[tid+512], Go = gbuf[tid+768];
        float cc = sigmf(Gf)*v4[tid] + sigmf(Gi)*tanhf(Gg);
        float hh = sigmf(Go)*tanhf(cc);
        v4[tid] = cc; v3[tid] = hh;
      }
      __syncthreads();
      { float acc = b_d1[tid];
        for (int kq = 0; kq < 64; ++kq){
          acc += dot4(Wd1ih[(kq<<10) + tid], *(const float4*)&v3[kq*4]);
          acc += dot4(Wd1hh[(kq<<10) + tid], *(const float4*)&v5[kq*4]);
        }
        gbuf[tid] = acc; }
      __syncthreads();
      if (tid < 256){
        float Gi = gbuf[tid], Gf = gbuf[tid+256], Gg = gbuf[tid+512], Go = gbuf[tid+768];
        float cc = sigmf(Gf)*v6[tid] + sigmf(Gi)*tanhf(Gg);
        float hh = sigmf(Go)*tanhf(cc);
        v6[tid] = cc; v5[tid] = hh;
      }
      __syncthreads();
      { int j = tid & 255, c = tid >> 8;   // a2 = dh2 @ W2^T
        float a = 0.f;
        for (int k = c*64; k < c*64 + 64; ++k) a = fmaf(v5[k], W2T[k*256 + j], a);
        gbuf[tid] = a; }
      __syncthreads();
      if (tid < 256) v1[tid] = gbuf[tid] + gbuf[tid+256] + gbuf[tid+512] + gbuf[tid+768];
      __syncthreads();
    };

    int tau = 0, lastidx = 0;
    for (int p = 0; p < SS; ++p){
      int t0 = (p == 0) ? 0 : lastidx;
      if (p > 0) dec_cell();   // overlaps with upstream re-encode
      for (int t = t0; t < SS; ++t){
        ++tau;
        if (tid == 0) wait_ge(&flg[FC], (unsigned)tau, abw);
        __syncthreads();
        if (tid < 256) v0[tid] = lrel(&h2cw[t*256 + tid]);
        __syncthreads();
        { int j = tid & 255, c = tid >> 8;   // eW1 row t
          float a = 0.f;
          for (int k = c*64; k < c*64 + 64; ++k) a = fmaf(v0[k], W1T[k*256 + j], a);
          gbuf[tid] = a; }
        __syncthreads();
        if (tid < 256) big1[t*256 + tid] = gbuf[tid] + gbuf[tid+256] + gbuf[tid+512] + gbuf[tid+768];
        __syncthreads();
      }
      if (p == 0){
        if (tid < 256){
          v3[tid] = lrel(&h1cw[63*256 + tid]);
          v4[tid] = lrel(&dc1i[tid]);
          v5[tid] = lrel(&h2cw[63*256 + tid]);
          v6[tid] = lrel(&dc2i[tid]);
          v2[tid] = lrel(&h2cw[0*256 + tid]);
        }
        __syncthreads();
        dec_cell();
      }
      // scores: 16 lanes per t
      { int t = tid >> 4, r = tid & 15;
        float a = 0.f;
        for (int j = r; j < HH; j += 16) a += vv[j] * tanhf(big1[t*256 + j] + v1[j]);
        a += __shfl_xor(a, 8, 16);
        a += __shfl_xor(a, 4, 16);
        a += __shfl_xor(a, 2, 16);
        a += __shfl_xor(a, 1, 16);
        if (r == 0) scr[t] = msk[t] ? -3.0e38f : a; }
      __syncthreads();
      // argmax FIRST (critical path: upstream stages wait on idx)
      if (tid < SS){
        float sv = scr[tid];
        float m = sv; int mi = tid;
#pragma unroll
        for (int o = 32; o >= 1; o >>= 1){
          float ov = __shfl_xor(m, o, 64);
          int oi = __shfl_xor(mi, o, 64);
          if (ov > m || (ov == m && oi < mi)){ m = ov; mi = oi; }
        }
        if (tid == 0){ ibc[1] = mi; smax_s = m; }
      }
      __syncthreads();
      int idx = ibc[1];
      lastidx = idx;
      if (p < SS-1){
        if (tid < 256) v2[tid] = lrel(&h2cw[idx*256 + tid]);  // dins BEFORE publish
        drain_vm();
        __syncthreads();
        if (tid == 0) fst(&flg[FD], ((unsigned)(p+1) << 8) | (unsigned)idx);
      }
      // softmax + output stores: off the critical path
      if (tid < SS){
        float sv = scr[tid];
        float e = expf(sv - smax_s);
        float ssum = e;
#pragma unroll
        for (int o = 32; o >= 1; o >>= 1) ssum += __shfl_xor(ssum, o, 64);
        out[((size_t)b*SS + p)*SS + tid] = e / ssum;
        if (tid == 0){
          msk[idx] = 1;
          out[(size_t)BB*SS*SS + (size_t)b*SS + p] = (float)idx;
        }
      }
      __syncthreads();
    }
  }
}

extern "C" void kernel_launch(void* const* d_in, const int* in_sizes, int n_in,
                              void* d_out, int out_size, void* d_ws, size_t ws_size,
                              hipStream_t stream) {
  const float* inputs = (const float*)d_in[0];
  const float* W_emb  = (const float*)d_in[1];
  const float* b_emb  = (const float*)d_in[2];
  const float* e_Wih0 = (const float*)d_in[3];
  const float* e_Whh0 = (const float*)d_in[4];
  const float* e_b0   = (const float*)d_in[5];
  const float* e_Wih1 = (const float*)d_in[6];
  const float* e_Whh1 = (const float*)d_in[7];
  const float* e_b1   = (const float*)d_in[8];
  const float* d_Wih0 = (const float*)d_in[9];
  const float* d_Whh0 = (const float*)d_in[10];
  const float* d_b0   = (const float*)d_in[11];
  const float* d_Wih1 = (const float*)d_in[12];
  const float* d_Whh1 = (const float*)d_in[13];
  const float* d_b1   = (const float*)d_in[14];
  const float* W1     = (const float*)d_in[15];
  const float* W2     = (const float*)d_in[16];
  const float* v      = (const float*)d_in[17];
  float* ws  = (float*)d_ws;
  float* out = (float*)d_out;

  size_t need = ((size_t)X1B_OFF + 32u*65536u) * 4u;
  int useX1B = (ws_size >= need) ? 1 : 0;

  zflags_k<<<dim3(9), dim3(1024), 0, stream>>>(ws);
  pack_transpose_k<<<dim3(16, 4, 8), dim3(256), 0, stream>>>(
      e_Wih0, e_Whh0, e_Wih1, e_Whh1, d_Wih0, d_Whh0, d_Wih1, d_Whh1, ws);
  transpose256_k<<<dim3(8, 8, 2), dim3(256), 0, stream>>>(W1, W2, ws);
  ptrnet_k<<<dim3(BB*4), dim3(NT), 0, stream>>>(
      inputs, W_emb, b_emb, e_b0, e_b1, d_b0, d_b1, v, ws, out, useX1B);
}

// Round 12
// 22160.921 us; speedup vs baseline: 1.0242x; 1.0242x over previous
//
#include <hip/hip_runtime.h>
#include <math.h>

#define BB 32
#define SS 64
#define HH 256
#define G4 1024
#define NT 1024

// ws float offsets
//  [0]        8 gate mats packed k-major f4 (R2 format), 262144 floats each
//  W1T_OFF    W1T k-major 256x256; W2T_OFF likewise
//  PB_OFF     per-batch: X1[64][1024], h1cw[64][256], p2 ring[16][1024],
//             h2cw[64][256], dc1i[256], dc2i[256]
//  FLG_OFF    per-batch 8 padded flag lines (32 words each); abort line after
//  X1B_OFF    optional per-batch X1alt[64][1024] (guarded by ws_size)
#define W1T_OFF 2097152
#define W2T_OFF 2162688
#define PB_OFF  2228224
#define PBB     115712
#define OX1     0
#define OH1     65536
#define OP2     81920
#define OH2     98304
#define ODC1    114688
#define ODC2    114944
#define FLG_OFF (PB_OFF + 32*PBB)
#define NFLGW   (32*256 + 32)
#define X1B_OFF (FLG_OFF + NFLGW)
#define FA 0
#define FB 32
#define FC 64
#define FD 96

__device__ __forceinline__ float sigmf(float x){ return 1.f/(1.f+expf(-x)); }
__device__ __forceinline__ float dot4(float4 a, float4 b){
  return fmaf(a.x,b.x,fmaf(a.y,b.y,fmaf(a.z,b.z,a.w*b.w)));
}
// Relaxed agent-scope transport (R7-proven). Ordering: payload srel ->
// drain_vm -> barrier -> flag fst. One-directional waits only.
__device__ __forceinline__ void fst(unsigned* p, unsigned v){
  __hip_atomic_store(p, v, __ATOMIC_RELAXED, __HIP_MEMORY_SCOPE_AGENT);
}
__device__ __forceinline__ unsigned fld(unsigned* p){
  return __hip_atomic_load(p, __ATOMIC_RELAXED, __HIP_MEMORY_SCOPE_AGENT);
}
__device__ __forceinline__ void srel(float* p, float v){
  __hip_atomic_store(p, v, __ATOMIC_RELAXED, __HIP_MEMORY_SCOPE_AGENT);
}
__device__ __forceinline__ float lrel(const float* p){
  return __hip_atomic_load((float*)p, __ATOMIC_RELAXED, __HIP_MEMORY_SCOPE_AGENT);
}
__device__ __forceinline__ void drain_vm(){
  asm volatile("s_waitcnt vmcnt(0)" ::: "memory");
}
__device__ __forceinline__ int wait_ge(unsigned* p, unsigned want, unsigned* ab){
  int it = 0;
  for(;;){
    unsigned v = fld(p);
    if (v >= want) return (int)v;
    if ((++it & 2047) == 0){
      if (fld(ab) != 0u) return -1;
      if (it > (1<<23)){ fst(ab, 1u); return -1; }
    }
    __builtin_amdgcn_s_sleep(2);
  }
}

__global__ void zflags_k(float* ws){
  unsigned* f = (unsigned*)(ws + FLG_OFF);
  int i = blockIdx.x*1024 + threadIdx.x;
  if (i < NFLGW) f[i] = 0u;
}

// R2-validated pack: dst[((k>>2)*1024 + g)*4 + (k&3)] = src[g*256 + k]
__global__ void pack_transpose_k(const float* __restrict__ s0, const float* __restrict__ s1,
                                 const float* __restrict__ s2, const float* __restrict__ s3,
                                 const float* __restrict__ s4, const float* __restrict__ s5,
                                 const float* __restrict__ s6, const float* __restrict__ s7,
                                 float* __restrict__ ws) {
    __shared__ float tile[64][65];
    const float* srcs[8] = {s0, s1, s2, s3, s4, s5, s6, s7};
    const float* src = srcs[blockIdx.z];
    float* dst = ws + (size_t)blockIdx.z * (G4 * HH);
    int gblk = blockIdx.x * 64;
    int kblk = blockIdx.y * 64;
    for (int q = threadIdx.x; q < 64 * 64; q += 256) {
        int r = q >> 6, c = q & 63;
        tile[r][c] = src[(size_t)(gblk + r) * HH + (kblk + c)];
    }
    __syncthreads();
    for (int q = threadIdx.x; q < 64 * 64; q += 256) {
        int r = q & 3;
        int gl = (q >> 2) & 63;
        int k0l = q >> 8;
        int dsti = (((kblk >> 2) + k0l) * G4 + gblk + gl) * 4 + r;
        dst[dsti] = tile[gl][k0l * 4 + r];
    }
}

// dst[k*256+j] = src[j*256+k]
__global__ void transpose256_k(const float* __restrict__ W1, const float* __restrict__ W2,
                               float* __restrict__ ws) {
    __shared__ float tile[32][33];
    const float* src = blockIdx.z ? W2 : W1;
    float* dst = ws + (blockIdx.z ? W2T_OFF : W1T_OFF);
    int j0 = blockIdx.x * 32, k0 = blockIdx.y * 32;
    int tx = threadIdx.x & 31, ty = threadIdx.x >> 5;
    for (int i = ty; i < 32; i += 8) tile[i][tx] = src[(size_t)(j0 + i) * HH + k0 + tx];
    __syncthreads();
    for (int i = ty; i < 32; i += 8) dst[(size_t)(k0 + i) * HH + j0 + tx] = tile[tx][i];
}

__global__ void __launch_bounds__(NT) ptrnet_k(
    const float* __restrict__ inputs, const float* __restrict__ W_emb,
    const float* __restrict__ b_emb,
    const float* __restrict__ b_e0, const float* __restrict__ b_e1,
    const float* __restrict__ b_d0, const float* __restrict__ b_d1,
    const float* __restrict__ vv,
    float* __restrict__ ws, float* __restrict__ out, int useX1B) {
  const int g = blockIdx.x;
  const int role = g & 3;   // A/B/C/D; %8 striping -> each XCD hosts one role
  const int b = g >> 2;
  const int tid = threadIdx.x;

  const float4* ws4 = (const float4*)ws;
  const float4* We0ih = ws4 + 0*65536;
  const float4* We0hh = ws4 + 1*65536;
  const float4* We1ih = ws4 + 2*65536;
  const float4* We1hh = ws4 + 3*65536;
  const float4* Wd0ih = ws4 + 4*65536;
  const float4* Wd0hh = ws4 + 5*65536;
  const float4* Wd1ih = ws4 + 6*65536;
  const float4* Wd1hh = ws4 + 7*65536;
  const float* W1T = ws + W1T_OFF;
  const float* W2T = ws + W2T_OFF;

  float* pb   = ws + PB_OFF + (size_t)b * PBB;
  float* X1   = pb + OX1;    // A-private
  float* h1cw = pb + OH1;    // A -> B
  float* p2cw = pb + OP2;    // B -> C, ring 16
  float* h2cw = pb + OH2;    // C -> D
  float* dc1i = pb + ODC1;   // A -> D (pass-0 finals)
  float* dc2i = pb + ODC2;   // C -> D
  float* X1B  = ws + X1B_OFF + (size_t)b * 65536;  // A-private (guarded)
  unsigned* Wf  = (unsigned*)(ws + FLG_OFF);
  unsigned* flg = Wf + b*256;   // padded: each flag its own 128B line
  unsigned* abw = Wf + 32*256;

  __shared__ float big0[16384];  // A: preE->c1c; C: c2c; D: preE
  __shared__ float big1[16384];  // A: init staging; D: eW1
  __shared__ float gbuf[1024];
  __shared__ float v0[256], v1[256], v2[256], v3[256], v4[256], v5[256], v6[256];
  __shared__ float scr[64];
  __shared__ int msk[64];
  __shared__ int ibc[2];

  // ================= role A: layer-1 recurrence =================
  if (role == 0) {
    for (int i = tid; i < SS*HH; i += NT){
      int t = i >> 8, j = i & 255;
      const float* xr = inputs + ((size_t)b*SS + t)*8;
      float acc = b_emb[j];
#pragma unroll
      for (int d = 0; d < 8; ++d) acc = fmaf(xr[d], W_emb[j*8+d], acc);
      big0[i] = acc;  // preE
    }
    __syncthreads();
    // X1 (+X1alt) init: 16 tiles of 4 t, one weight stream serves both variants
    for (int tile = 0; tile < 16; ++tile){
      { int tt = tid >> 8, j = tid & 255;
        float pe = big0[(tile*4+tt)*256 + j];
        gbuf[tid] = tanhf(pe);
        big1[tid] = tanhf(pe + W_emb[j*8 + 7]); }
      __syncthreads();
      float a0=0.f,a1=0.f,a2=0.f,a3=0.f;
      float c0=0.f,c1=0.f,c2=0.f,c3=0.f;
      for (int kq = 0; kq < 64; ++kq){
        float4 w = We0ih[(kq<<10) + tid];
        a0 += dot4(w, *(const float4*)&gbuf[   0 + kq*4]);
        a1 += dot4(w, *(const float4*)&gbuf[ 256 + kq*4]);
        a2 += dot4(w, *(const float4*)&gbuf[ 512 + kq*4]);
        a3 += dot4(w, *(const float4*)&gbuf[ 768 + kq*4]);
        c0 += dot4(w, *(const float4*)&big1[   0 + kq*4]);
        c1 += dot4(w, *(const float4*)&big1[ 256 + kq*4]);
        c2 += dot4(w, *(const float4*)&big1[ 512 + kq*4]);
        c3 += dot4(w, *(const float4*)&big1[ 768 + kq*4]);
      }
      float bg = b_e0[tid];
      X1[(tile*4+0)*1024 + tid] = bg + a0;
      X1[(tile*4+1)*1024 + tid] = bg + a1;
      X1[(tile*4+2)*1024 + tid] = bg + a2;
      X1[(tile*4+3)*1024 + tid] = bg + a3;
      if (useX1B){
        X1B[(tile*4+0)*1024 + tid] = bg + c0;
        X1B[(tile*4+1)*1024 + tid] = bg + c1;
        X1B[(tile*4+2)*1024 + tid] = bg + c2;
        X1B[(tile*4+3)*1024 + tid] = bg + c3;
      }
      __syncthreads();
    }
    // big0 becomes c1c from here
    if (tid < 256) v0[tid] = 0.f;  // h1
    __syncthreads();
    int tau = 0;
    for (int p = 0; p < SS; ++p){
      int t0 = 0;
      float xr0 = 0.f;
      if (p > 0){
        if (tid == 0){
          int iv = wait_ge(&flg[FD], (unsigned)p << 8, abw);
          ibc[0] = (iv < 0) ? 0 : (iv & 255);
        }
        __syncthreads();
        t0 = ibc[0];
        if (useX1B){
          xr0 = X1B[t0*1024 + tid];     // precomputed flagged row
        } else {
          if (tid < 256){               // fallback: recompute embt + GEMV
            const float* xr = inputs + ((size_t)b*SS + t0)*8;
            float pe = b_emb[tid];
#pragma unroll
            for (int d = 0; d < 8; ++d) pe = fmaf(xr[d], W_emb[tid*8+d], pe);
            v1[tid] = tanhf(pe + W_emb[tid*8 + 7]);
          }
          __syncthreads();
          float accR = 0.f;
          for (int kq = 0; kq < 64; ++kq)
            accR += dot4(We0ih[(kq<<10) + tid], *(const float4*)&v1[kq*4]);
          xr0 = b_e0[tid] + accR;
        }
        X1[t0*1024 + tid] = xr0;        // permanent (cur flags accumulate)
        if (tid < 256) v0[tid] = (t0 > 0) ? lrel(&h1cw[(t0-1)*256 + tid]) : 0.f;
        __syncthreads();
      }
      for (int t = t0; t < SS; ++t){
        ++tau;
        float xv = (p > 0 && t == t0) ? xr0 : X1[t*1024 + tid];  // load in flight during GEMV
        float acc = 0.f;
        for (int kq = 0; kq < 64; ++kq)
          acc += dot4(We0hh[(kq<<10) + tid], *(const float4*)&v0[kq*4]);
        gbuf[tid] = acc + xv;
        __syncthreads();
        if (tid < 256){
          float Gi = gbuf[tid], Gf = gbuf[tid+256], Gg = gbuf[tid+512], Go = gbuf[tid+768];
          float cp = (t == 0) ? 0.f : big0[(t-1)*256 + tid];
          float cc = sigmf(Gf)*cp + sigmf(Gi)*tanhf(Gg);
          float hh = sigmf(Go)*tanhf(cc);
          big0[t*256 + tid] = cc; v0[tid] = hh;
          srel(&h1cw[t*256 + tid], hh);
          if (p == 0 && t == SS-1) srel(&dc1i[tid], cc);
        }
        drain_vm();
        __syncthreads();
        if (tid == 0) fst(&flg[FA], (unsigned)tau);
      }
    }
  }
  // ================= role B: p2(t) = b_e1 + Wih1 . h1(t) =================
  else if (role == 1) {
    int tau = 0;
    for (int p = 0; p < SS; ++p){
      int t0 = 0;
      if (p > 0){
        if (tid == 0){
          int iv = wait_ge(&flg[FD], (unsigned)p << 8, abw);
          ibc[0] = (iv < 0) ? 0 : (iv & 255);
        }
        __syncthreads();
        t0 = ibc[0];
      }
      for (int t = t0; t < SS; ++t){
        ++tau;
        if (tid == 0){
          wait_ge(&flg[FA], (unsigned)tau, abw);                       // progA
          if (tau > 16) wait_ge(&flg[FC], (unsigned)(tau-16), abw);    // ring backpressure
        }
        __syncthreads();
        if (tid < 256) v0[tid] = lrel(&h1cw[t*256 + tid]);
        __syncthreads();
        float acc = b_e1[tid];
        for (int kq = 0; kq < 64; ++kq)
          acc += dot4(We1ih[(kq<<10) + tid], *(const float4*)&v0[kq*4]);
        srel(&p2cw[(tau & 15)*1024 + tid], acc);
        drain_vm();
        __syncthreads();
        if (tid == 0) fst(&flg[FB], (unsigned)tau);
      }
    }
  }
  // ================= role C: layer-2 recurrence =================
  else if (role == 2) {
    int tau = 0;
    for (int p = 0; p < SS; ++p){
      int t0 = 0;
      if (p > 0){
        if (tid == 0){
          int iv = wait_ge(&flg[FD], (unsigned)p << 8, abw);
          ibc[0] = (iv < 0) ? 0 : (iv & 255);
        }
        __syncthreads();
        t0 = ibc[0];
      }
      if (tid < 256) v0[tid] = (t0 > 0) ? lrel(&h2cw[(t0-1)*256 + tid]) : 0.f;
      __syncthreads();
      for (int t = t0; t < SS; ++t){
        ++tau;
        if (tid == 0) wait_ge(&flg[FB], (unsigned)tau, abw);
        __syncthreads();
        float p2v = lrel(&p2cw[(tau & 15)*1024 + tid]);  // in flight during GEMV
        float acc = 0.f;
        for (int kq = 0; kq < 64; ++kq)
          acc += dot4(We1hh[(kq<<10) + tid], *(const float4*)&v0[kq*4]);
        gbuf[tid] = acc + p2v;
        __syncthreads();
        if (tid < 256){
          float Gi = gbuf[tid], Gf = gbuf[tid+256], Gg = gbuf[tid+512], Go = gbuf[tid+768];
          float cp = (t == 0) ? 0.f : big0[(t-1)*256 + tid];   // c2c
          float cc = sigmf(Gf)*cp + sigmf(Gi)*tanhf(Gg);
          float hh = sigmf(Go)*tanhf(cc);
          big0[t*256 + tid] = cc; v0[tid] = hh;
          srel(&h2cw[t*256 + tid], hh);
          if (p == 0 && t == SS-1) srel(&dc2i[tid], cc);
        }
        drain_vm();
        __syncthreads();
        if (tid == 0) fst(&flg[FC], (unsigned)tau);
      }
    }
  }
  // ================= role D: eW1, decoder cell, attention, argmax =================
  else {
    for (int i = tid; i < SS*HH; i += NT){
      int t = i >> 8, j = i & 255;
      const float* xr = inputs + ((size_t)b*SS + t)*8;
      float acc = b_emb[j];
#pragma unroll
      for (int d = 0; d < 8; ++d) acc = fmaf(xr[d], W_emb[j*8+d], acc);
      big0[i] = acc;  // preE, kept whole run
    }
    if (tid < 64) msk[tid] = 0;
    __syncthreads();

    // v2=dins v3=dh1 v4=dc1 v5=dh2 v6=dc2 v1=a2
    auto dec_cell = [&](){
      { float acc = b_d0[tid];
        for (int kq = 0; kq < 64; ++kq){
          acc += dot4(Wd0ih[(kq<<10) + tid], *(const float4*)&v2[kq*4]);
          acc += dot4(Wd0hh[(kq<<10) + tid], *(const float4*)&v3[kq*4]);
        }
        gbuf[tid] = acc; }
      __syncthreads();
      if (tid < 256){
        float Gi = gbuf[tid], Gf = gbuf[tid+256], Gg = gbuf[tid+512], Go = gbuf[tid+768];
        float cc = sigmf(Gf)*v4[tid] + sigmf(Gi)*tanhf(Gg);
        float hh = sigmf(Go)*tanhf(cc);
        v4[tid] = cc; v3[tid] = hh;
      }
      __syncthreads();
      { float acc = b_d1[tid];
        for (int kq = 0; kq < 64; ++kq){
          acc += dot4(Wd1ih[(kq<<10) + tid], *(const float4*)&v3[kq*4]);
          acc += dot4(Wd1hh[(kq<<10) + tid], *(const float4*)&v5[kq*4]);
        }
        gbuf[tid] = acc; }
      __syncthreads();
      if (tid < 256){
        float Gi = gbuf[tid], Gf = gbuf[tid+256], Gg = gbuf[tid+512], Go = gbuf[tid+768];
        float cc = sigmf(Gf)*v6[tid] + sigmf(Gi)*tanhf(Gg);
        float hh = sigmf(Go)*tanhf(cc);
        v6[tid] = cc; v5[tid] = hh;
      }
      __syncthreads();
      { int j = tid & 255, c = tid >> 8;   // a2 = dh2 @ W2^T
        float a = 0.f;
        for (int k = c*64; k < c*64 + 64; ++k) a = fmaf(v5[k], W2T[k*256 + j], a);
        gbuf[tid] = a; }
      __syncthreads();
      if (tid < 256) v1[tid] = gbuf[tid] + gbuf[tid+256] + gbuf[tid+512] + gbuf[tid+768];
      __syncthreads();
    };

    int tau = 0, lastidx = 0;
    for (int p = 0; p < SS; ++p){
      int t0 = (p == 0) ? 0 : lastidx;
      if (p > 0) dec_cell();   // overlaps with upstream re-encode
      for (int t = t0; t < SS; ++t){
        ++tau;
        if (tid == 0) wait_ge(&flg[FC], (unsigned)tau, abw);
        __syncthreads();
        if (tid < 256) v0[tid] = lrel(&h2cw[t*256 + tid]);
        __syncthreads();
        { int j = tid & 255, c = tid >> 8;   // eW1 row t
          float a = 0.f;
          for (int k = c*64; k < c*64 + 64; ++k) a = fmaf(v0[k], W1T[k*256 + j], a);
          gbuf[tid] = a; }
        __syncthreads();
        if (tid < 256) big1[t*256 + tid] = gbuf[tid] + gbuf[tid+256] + gbuf[tid+512] + gbuf[tid+768];
        __syncthreads();
      }
      if (p == 0){
        if (tid < 256){
          v3[tid] = lrel(&h1cw[63*256 + tid]);
          v4[tid] = lrel(&dc1i[tid]);
          v5[tid] = lrel(&h2cw[63*256 + tid]);
          v6[tid] = lrel(&dc2i[tid]);
          v2[tid] = lrel(&h2cw[0*256 + tid]);
        }
        __syncthreads();
        dec_cell();
      }
      // scores: 16 lanes per t
      { int t = tid >> 4, r = tid & 15;
        float a = 0.f;
        for (int j = r; j < HH; j += 16) a += vv[j] * tanhf(big1[t*256 + j] + v1[j]);
        a += __shfl_xor(a, 8, 16);
        a += __shfl_xor(a, 4, 16);
        a += __shfl_xor(a, 2, 16);
        a += __shfl_xor(a, 1, 16);
        if (r == 0) scr[t] = msk[t] ? -3.0e38f : a; }
      __syncthreads();
      if (tid < SS){
        float sv = scr[tid];
        float m = sv; int mi = tid;
#pragma unroll
        for (int o = 32; o >= 1; o >>= 1){
          float ov = __shfl_xor(m, o, 64);
          int oi = __shfl_xor(mi, o, 64);
          if (ov > m || (ov == m && oi < mi)){ m = ov; mi = oi; }
        }
        float e = expf(sv - m);
        float ssum = e;
#pragma unroll
        for (int o = 32; o >= 1; o >>= 1) ssum += __shfl_xor(ssum, o, 64);
        out[((size_t)b*SS + p)*SS + tid] = e / ssum;
        if (tid == 0){
          msk[mi] = 1;
          out[(size_t)BB*SS*SS + (size_t)b*SS + p] = (float)mi;
          ibc[1] = mi;
        }
      }
      __syncthreads();
      int idx = ibc[1];
      lastidx = idx;
      if (p < SS-1){
        if (tid < 256) v2[tid] = lrel(&h2cw[idx*256 + tid]);  // dins, read BEFORE publish
        drain_vm();
        __syncthreads();
        if (tid == 0) fst(&flg[FD], ((unsigned)(p+1) << 8) | (unsigned)idx);
      }
    }
  }
}

extern "C" void kernel_launch(void* const* d_in, const int* in_sizes, int n_in,
                              void* d_out, int out_size, void* d_ws, size_t ws_size,
                              hipStream_t stream) {
  const float* inputs = (const float*)d_in[0];
  const float* W_emb  = (const float*)d_in[1];
  const float* b_emb  = (const float*)d_in[2];
  const float* e_Wih0 = (const float*)d_in[3];
  const float* e_Whh0 = (const float*)d_in[4];
  const float* e_b0   = (const float*)d_in[5];
  const float* e_Wih1 = (const float*)d_in[6];
  const float* e_Whh1 = (const float*)d_in[7];
  const float* e_b1   = (const float*)d_in[8];
  const float* d_Wih0 = (const float*)d_in[9];
  const float* d_Whh0 = (const float*)d_in[10];
  const float* d_b0   = (const float*)d_in[11];
  const float* d_Wih1 = (const float*)d_in[12];
  const float* d_Whh1 = (const float*)d_in[13];
  const float* d_b1   = (const float*)d_in[14];
  const float* W1     = (const float*)d_in[15];
  const float* W2     = (const float*)d_in[16];
  const float* v      = (const float*)d_in[17];
  float* ws  = (float*)d_ws;
  float* out = (float*)d_out;

  size_t need = ((size_t)X1B_OFF + 32u*65536u) * 4u;
  int useX1B = (ws_size >= need) ? 1 : 0;

  zflags_k<<<dim3(9), dim3(1024), 0, stream>>>(ws);
  pack_transpose_k<<<dim3(16, 4, 8), dim3(256), 0, stream>>>(
      e_Wih0, e_Whh0, e_Wih1, e_Whh1, d_Wih0, d_Whh0, d_Wih1, d_Whh1, ws);
  transpose256_k<<<dim3(8, 8, 2), dim3(256), 0, stream>>>(W1, W2, ws);
  ptrnet_k<<<dim3(BB*4), dim3(NT), 0, stream>>>(
      inputs, W_emb, b_emb, e_b0, e_b1, d_b0, d_b1, v, ws, out, useX1B);
}